// Round 12
// baseline (477.588 us; speedup 1.0000x reference)
//
#include <hip/hip_runtime.h>

typedef unsigned short u16;
typedef _Float16 f16;
typedef __attribute__((ext_vector_type(8))) f16 f16x8;
typedef __attribute__((ext_vector_type(4))) float fx4;
typedef __attribute__((ext_vector_type(8))) u16 u16x8;
typedef __attribute__((ext_vector_type(4))) u16 u16x4;

#define SZE 8388608u  // 16384*512 elements per [B*L, D] matrix

__device__ __forceinline__ u16 f2h_bits(float x) {
  union { f16 h; u16 u; } v; v.h = (f16)x; return v.u;
}

// async global->LDS, 16B per lane; dest is wave-uniform base + lane*16.
__device__ __forceinline__ void gl2lds16(const void* g, void* l) {
  __builtin_amdgcn_global_load_lds(
      (const __attribute__((address_space(1))) unsigned int*)g,
      (__attribute__((address_space(3))) unsigned int*)l, 16, 0, 0);
}

// ---------------- kernel 1: fp32 -> fp16 convert of both inputs ------------
// (R9 form. R10's blob-layout rewrite of the producers caused nondeterminism
// on graph replay -- reverted wholesale, do not re-attempt without a way to
// localize the race.)
__global__ __launch_bounds__(256) void convert_x(const float* __restrict__ x0,
                                                 const float* __restrict__ x1,
                                                 u16* __restrict__ xh) {
  size_t i = ((size_t)blockIdx.x * 256 + threadIdx.x) * 8;
  const float* src = (i < SZE) ? (x0 + i) : (x1 + (i - SZE));
  float4 a = *(const float4*)(src);
  float4 b = *(const float4*)(src + 4);
  u16x8 o;
  o[0] = f2h_bits(a.x); o[1] = f2h_bits(a.y);
  o[2] = f2h_bits(a.z); o[3] = f2h_bits(a.w);
  o[4] = f2h_bits(b.x); o[5] = f2h_bits(b.y);
  o[6] = f2h_bits(b.z); o[7] = f2h_bits(b.w);
  *(u16x8*)(xh + i) = o;
}

// ---------------- kernel 2: W [K][N] fp32 -> Wt [N][K] fp16 ----------------
__global__ __launch_bounds__(256) void wtrans(
    const float* __restrict__ w0, const float* __restrict__ w1,
    const float* __restrict__ w2, const float* __restrict__ w3,
    const float* __restrict__ w4, const float* __restrict__ w5,
    u16* __restrict__ wt) {
  __shared__ float tile[32][33];
  const int z = blockIdx.z;
  const float* W = z == 0 ? w0 : z == 1 ? w1 : z == 2 ? w2
                 : z == 3 ? w3 : z == 4 ? w4 : w5;
  u16* WT = wt + (size_t)z * 262144u;
  const int k0 = blockIdx.x * 32, n0 = blockIdx.y * 32;
  const int tx = threadIdx.x, ty = threadIdx.y;  // 32 x 8
  for (int j = 0; j < 32; j += 8)
    tile[ty + j][tx] = W[(size_t)(k0 + ty + j) * 512 + n0 + tx];
  __syncthreads();
  for (int j = 0; j < 32; j += 8)
    WT[(size_t)(n0 + ty + j) * 512 + k0 + tx] = f2h_bits(tile[tx][ty + j]);
}

// ---------------- kernel 3: six projections, C = X*W + b -------------------
// R9 form (passed at 474.5us). Proj optimization ledger is closed: dbuf (R7),
// cst-epilogue (R8), occupancy 3/CU (R9) all neutral; input-blob (R10) failed
// replay determinism. Keep as-is.
// Blob layouts (consumed linearly by attn staging):
//  K blob: per b, per 32-key tile kt: slot p = dchunk*32+key holds
//          K[key][dchunk*8 .. +8).
//  V blob: per b, per tile kt: slot p = kc*512 + d holds
//          V[token kt*32+kc*8 .. +8)[d].
__global__ __launch_bounds__(256, 3) void proj_gemm(
    const u16* __restrict__ xh, const u16* __restrict__ wt,
    u16* __restrict__ qkv,
    const float* __restrict__ b0, const float* __restrict__ b1,
    const float* __restrict__ b2, const float* __restrict__ b3,
    const float* __restrict__ b4, const float* __restrict__ b5) {
  const int proj = blockIdx.z;
  const u16* X = xh + (proj < 3 ? 0u : SZE);
  const u16* W = wt + (size_t)proj * 262144u;
  u16* out = qkv + (size_t)proj * SZE;
  const float* bias = proj == 0 ? b0 : proj == 1 ? b1 : proj == 2 ? b2
                    : proj == 3 ? b3 : proj == 4 ? b4 : b5;
  const int m0 = blockIdx.x * 128, n0 = blockIdx.y * 128;
  const int t = threadIdx.x, lane = t & 63, w = t >> 6;
  const int wr = w >> 1, wc = w & 1, ml = lane & 15, q = lane >> 4;
  __shared__ u16 sA[2][4096], sB[2][4096];
  fx4 acc[4][4] = {};
  // prologue: stage k-tile 0 into buffer 0
  for (int r = 0; r < 2; ++r) {
    int ci = r * 256 + t;
    int cq = ci >> 7, cm = ci & 127;
    gl2lds16(X + (size_t)(m0 + cm) * 512 + cq * 8, sA[0] + ci * 8);
    gl2lds16(W + (size_t)(n0 + cm) * 512 + cq * 8, sB[0] + ci * 8);
  }
  __syncthreads();
  for (int kt = 0; kt < 16; ++kt) {
    const int c = kt & 1;
    if (kt < 15) {
      const int k0 = (kt + 1) * 32;
      for (int r = 0; r < 2; ++r) {
        int ci = r * 256 + t;
        int cq = ci >> 7, cm = ci & 127;
        gl2lds16(X + (size_t)(m0 + cm) * 512 + (k0 + cq * 8), sA[c ^ 1] + ci * 8);
        gl2lds16(W + (size_t)(n0 + cm) * 512 + (k0 + cq * 8), sB[c ^ 1] + ci * 8);
      }
    }
    f16x8 af[4], bf[4];
    for (int i = 0; i < 4; ++i) {
      af[i] = *(const f16x8*)(sA[c] + (q * 128 + wr * 64 + i * 16 + ml) * 8);
      bf[i] = *(const f16x8*)(sB[c] + (q * 128 + wc * 64 + i * 16 + ml) * 8);
    }
    for (int i = 0; i < 4; ++i)
      for (int j = 0; j < 4; ++j)
        acc[i][j] = __builtin_amdgcn_mfma_f32_16x16x32_f16(af[i], bf[j],
                                                           acc[i][j], 0, 0, 0);
    __syncthreads();
  }
  const int pm = proj % 3;  // 0=Q (row-major), 1=K blob, 2=V blob
  for (int j = 0; j < 4; ++j) {
    const int n = n0 + wc * 64 + j * 16 + ml;
    const float bv = bias[n];
    for (int i = 0; i < 4; ++i) {
      const int mb = m0 + wr * 64 + i * 16 + q * 4;
      if (pm == 0) {
        for (int r = 0; r < 4; ++r)
          out[(size_t)(mb + r) * 512 + n] = f2h_bits(acc[i][j][r] + bv);
      } else if (pm == 1) {
        for (int r = 0; r < 4; ++r) {
          const int m = mb + r, kq = m & 2047;
          size_t a = (size_t)(m >> 11) * 1048576u + (size_t)(kq >> 5) * 16384u
                   + (size_t)((n >> 3) * 32 + (kq & 31)) * 8u + (size_t)(n & 7);
          out[a] = f2h_bits(acc[i][j][r] + bv);
        }
      } else {
        const int l = mb & 2047;
        size_t a = (size_t)(mb >> 11) * 1048576u + (size_t)(l >> 5) * 16384u
                 + (size_t)(((l & 31) >> 3) * 512 + n) * 8u + (size_t)(l & 7);
        u16x4 pk;
        for (int r = 0; r < 4; ++r) pk[r] = f2h_bits(acc[i][j][r] + bv);
        *(u16x4*)(out + a) = pk;
      }
    }
  }
}

// ---------------- kernel 4: flash cross-attention v13 ----------------------
// v11 (tile-blob staging, proven ~235us) + ONE isolated change: T5
// s_setprio(1) around the QK and PV MFMA clusters. The 8 waves drift within
// the single-barrier iteration; when a SIMD's two waves are in different
// phases (one VALU/softmax, one MFMA), priority keeps the matrix pipe fed.
// Guide's isolated attn measurement: +4-7%. Adds no registers, no
// control-flow-dependent live state (v12 spill lesson respected).
__global__ __launch_bounds__(512, 2) void attn_kernel(const u16* __restrict__ qkv,
                                                      float* __restrict__ out) {
  const int t = threadIdx.x, lane = t & 63, w = t >> 6;  // w in 0..7
  const int ml = lane & 15, q = lane >> 4;
  // XCD swizzle: xcd = n&7 owns (b,tt) groups {2*xcd, 2*xcd+1}
  const int n = blockIdx.x;
  const int xcd = n & 7, slot = n >> 3;
  const int g = xcd * 2 + (slot >> 4);
  const int qt = slot & 15;
  const int b = g >> 1, tt = g & 1;

  const u16* Q  = qkv + (tt ? (size_t)3 * SZE : (size_t)0);
  const u16* K  = qkv + (tt ? (size_t)1 * SZE : (size_t)4 * SZE);
  const u16* Vt = qkv + (tt ? (size_t)5 * SZE : (size_t)2 * SZE);
  float* O = out + (tt ? (size_t)SZE : (size_t)0) +
             ((size_t)b * 2048 + qt * 128) * 512;
  const u16* Qb = Q + ((size_t)b * 2048 + qt * 128) * 512;
  const u16* Kb = K + (size_t)b * 1048576u;   // blob: [kt(64)][16384]
  const u16* Vb = Vt + (size_t)b * 1048576u;  // blob: [kt(64)][16384]

  __shared__ u16 sK[2][16384];   // 2 x 32KB, slot p: [dchunk(64)][key(32)]
  __shared__ u16 sV[2][16384];   // 2 x 32KB, slot p: [kc(4)][d(512)]
  __shared__ u16 sP[8 * 640];    // per-wave 16 rows x stride 40

  // Q A-frags for this wave's 16 rows (64 VGPR, resident all 64 iters)
  f16x8 qf[16];
  {
    const u16* qrow = Qb + (size_t)(w * 16 + ml) * 512 + q * 8;
#pragma unroll
    for (int ks = 0; ks < 16; ++ks) qf[ks] = *(const f16x8*)(qrow + ks * 32);
  }

  fx4 acc[32] = {};  // rows q*4+r (of wave's 16), col nj*16+ml  (128 VGPR)
  fx4 mrun = {-3.0e38f, -3.0e38f, -3.0e38f, -3.0e38f};
  fx4 lrun = {0.f, 0.f, 0.f, 0.f};
  u16* wp = sP + w * 640;

  // prestage tile 0 (linear: lane-consecutive 16B, fully coalesced)
#pragma unroll
  for (int r = 0; r < 4; ++r) {
    int p = r * 512 + t;
    gl2lds16(Kb + (size_t)p * 8, sK[0] + p * 8);
    gl2lds16(Vb + (size_t)p * 8, sV[0] + p * 8);
  }
  __syncthreads();

  for (int it = 0; it < 64; ++it) {
    const int c = it & 1;
    const u16* sKc = sK[c];
    const u16* sVc = sV[c];
    // ---- stage tile it+1 (linear blob reads); drained at end barrier ----
    if (it < 63) {
      const u16* Kn = Kb + (size_t)(it + 1) * 16384u;
      const u16* Vn = Vb + (size_t)(it + 1) * 16384u;
#pragma unroll
      for (int r = 0; r < 4; ++r) {
        int p = r * 512 + t;
        gl2lds16(Kn + (size_t)p * 8, sK[c ^ 1] + p * 8);
        gl2lds16(Vn + (size_t)p * 8, sV[c ^ 1] + p * 8);
      }
    }
    // ---- QK^T: this wave's 16 rows x 32 keys ----
    fx4 s0 = {0.f, 0.f, 0.f, 0.f}, s1 = {0.f, 0.f, 0.f, 0.f};
    __builtin_amdgcn_s_setprio(1);
#pragma unroll
    for (int ks = 0; ks < 16; ++ks) {
      f16x8 kf0 = *(const f16x8*)(sKc + ((ks * 4 + q) * 32 + ml) * 8);
      f16x8 kf1 = *(const f16x8*)(sKc + ((ks * 4 + q) * 32 + 16 + ml) * 8);
      s0 = __builtin_amdgcn_mfma_f32_16x16x32_f16(qf[ks], kf0, s0, 0, 0, 0);
      s1 = __builtin_amdgcn_mfma_f32_16x16x32_f16(qf[ks], kf1, s1, 0, 0, 0);
    }
    __builtin_amdgcn_s_setprio(0);
    // ---- online softmax, state in regs (rows = quad lanes q*4+r) ----
    fx4 mx, alpha, p0, p1, sm;
#pragma unroll
    for (int r = 0; r < 4; ++r) mx[r] = fmaxf(s0[r], s1[r]);
#pragma unroll
    for (int d = 1; d < 16; d <<= 1) {
      mx[0] = fmaxf(mx[0], __shfl_xor(mx[0], d));
      mx[1] = fmaxf(mx[1], __shfl_xor(mx[1], d));
      mx[2] = fmaxf(mx[2], __shfl_xor(mx[2], d));
      mx[3] = fmaxf(mx[3], __shfl_xor(mx[3], d));
    }
    bool need = false;
#pragma unroll
    for (int r = 0; r < 4; ++r) {
      float mn = fmaxf(mrun[r], mx[r]);
      alpha[r] = __expf(mrun[r] - mn);
      mrun[r] = mn;
      p0[r] = __expf(s0[r] - mn);
      p1[r] = __expf(s1[r] - mn);
      sm[r] = p0[r] + p1[r];
      need |= (alpha[r] != 1.0f);
    }
#pragma unroll
    for (int d = 1; d < 16; d <<= 1) {
      sm[0] += __shfl_xor(sm[0], d);
      sm[1] += __shfl_xor(sm[1], d);
      sm[2] += __shfl_xor(sm[2], d);
      sm[3] += __shfl_xor(sm[3], d);
    }
#pragma unroll
    for (int r = 0; r < 4; ++r) lrun[r] = alpha[r] * lrun[r] + sm[r];
    // ---- P -> wave-private slab (no barrier: same-wave lgkm ordering) ----
#pragma unroll
    for (int r = 0; r < 4; ++r) {
      wp[(q * 4 + r) * 40 + ml] = f2h_bits(p0[r]);
      wp[(q * 4 + r) * 40 + 16 + ml] = f2h_bits(p1[r]);
    }
    // ---- rescale acc (skip when no row saw a new max) ----
    if (__any(need)) {
#pragma unroll
      for (int nj = 0; nj < 32; ++nj) {
        acc[nj][0] *= alpha[0]; acc[nj][1] *= alpha[1];
        acc[nj][2] *= alpha[2]; acc[nj][3] *= alpha[3];
      }
    }
    f16x8 pf = *(const f16x8*)(wp + ml * 40 + q * 8);
    // ---- PV over all 512 d (one shared pf) ----
    __builtin_amdgcn_s_setprio(1);
#pragma unroll
    for (int nj = 0; nj < 32; ++nj) {
      f16x8 vf = *(const f16x8*)(sVc + (q * 512 + nj * 16 + ml) * 8);
      acc[nj] = __builtin_amdgcn_mfma_f32_16x16x32_f16(pf, vf, acc[nj], 0, 0, 0);
    }
    __builtin_amdgcn_s_setprio(0);
    __syncthreads();  // single barrier: drains next-iter staging + buffer flip
  }
  // ---- epilogue: O = acc / l (all wave-private) ----
  fx4 linv;
#pragma unroll
  for (int r = 0; r < 4; ++r) linv[r] = 1.0f / lrun[r];
  float* Ob = O + (size_t)(w * 16 + q * 4) * 512 + ml;
#pragma unroll
  for (int nj = 0; nj < 32; ++nj) {
#pragma unroll
    for (int r = 0; r < 4; ++r)
      Ob[(size_t)r * 512 + nj * 16] = acc[nj][r] * linv[r];
  }
}

extern "C" void kernel_launch(void* const* d_in, const int* in_sizes, int n_in,
                              void* d_out, int out_size, void* d_ws, size_t ws_size,
                              hipStream_t stream) {
  // ws layout (u16 elems): [xh: 2*SZE][wt: 6*512*512][qkv: 6*SZE]
  //   qkv order: 0=Qr 1=Kr(blob) 2=Vr^T(blob) 3=Qh 4=Kh(blob) 5=Vh^T(blob)
  u16* ws = (u16*)d_ws;
  u16* xh = ws;
  u16* wt = ws + 16777216u;            // 2*SZE
  u16* qkv = ws + 18350080u;           // 2*SZE + 6*262144

  convert_x<<<8192, 256, 0, stream>>>((const float*)d_in[0],
                                      (const float*)d_in[1], xh);
  wtrans<<<dim3(16, 16, 6), dim3(32, 8), 0, stream>>>(
      (const float*)d_in[2], (const float*)d_in[4], (const float*)d_in[6],
      (const float*)d_in[8], (const float*)d_in[10], (const float*)d_in[12], wt);
  proj_gemm<<<dim3(128, 4, 6), 256, 0, stream>>>(
      xh, wt, qkv,
      (const float*)d_in[3], (const float*)d_in[5], (const float*)d_in[7],
      (const float*)d_in[9], (const float*)d_in[11], (const float*)d_in[13]);
  attn_kernel<<<256, 512, 0, stream>>>(qkv, (float*)d_out);
}

// Round 13
// 463.831 us; speedup vs baseline: 1.0297x; 1.0297x over previous
//
#include <hip/hip_runtime.h>

typedef unsigned short u16;
typedef _Float16 f16;
typedef __attribute__((ext_vector_type(8))) f16 f16x8;
typedef __attribute__((ext_vector_type(4))) float fx4;
typedef __attribute__((ext_vector_type(8))) u16 u16x8;
typedef __attribute__((ext_vector_type(4))) u16 u16x4;

#define SZE 8388608u  // 16384*512 elements per [B*L, D] matrix

__device__ __forceinline__ u16 f2h_bits(float x) {
  union { f16 h; u16 u; } v; v.h = (f16)x; return v.u;
}

// async global->LDS, 16B per lane; dest is wave-uniform base + lane*16.
__device__ __forceinline__ void gl2lds16(const void* g, void* l) {
  __builtin_amdgcn_global_load_lds(
      (const __attribute__((address_space(1))) unsigned int*)g,
      (__attribute__((address_space(3))) unsigned int*)l, 16, 0, 0);
}

// ---- DPP 16-lane all-reduce (VALU-only; replaces ds_bpermute shfl chains).
// Reduce domain = 16 contiguous lanes (q*16..q*16+15) = one DPP row.
// quad_perm[1,0,3,2]=0xB1 (xor1), quad_perm[2,3,0,1]=0x4E (xor2); after
// those values are quad-uniform, so row_half_mirror(0x141) acts as xor4 and
// row_mirror(0x140) as xor8. Functionally verified in v9 (identical absmax).
// Straight-line, no extra live state (v12 spill lesson respected).
template <int C>
__device__ __forceinline__ float dppf(float x) {
  return __int_as_float(__builtin_amdgcn_update_dpp(
      __float_as_int(x), __float_as_int(x), C, 0xf, 0xf, false));
}
__device__ __forceinline__ float rowmax16(float x) {
  x = fmaxf(x, dppf<0xB1>(x));
  x = fmaxf(x, dppf<0x4E>(x));
  x = fmaxf(x, dppf<0x141>(x));
  x = fmaxf(x, dppf<0x140>(x));
  return x;
}
__device__ __forceinline__ float rowsum16(float x) {
  x += dppf<0xB1>(x);
  x += dppf<0x4E>(x);
  x += dppf<0x141>(x);
  x += dppf<0x140>(x);
  return x;
}

// ---------------- kernel 1: fp32 -> fp16 convert of both inputs ------------
__global__ __launch_bounds__(256) void convert_x(const float* __restrict__ x0,
                                                 const float* __restrict__ x1,
                                                 u16* __restrict__ xh) {
  size_t i = ((size_t)blockIdx.x * 256 + threadIdx.x) * 8;
  const float* src = (i < SZE) ? (x0 + i) : (x1 + (i - SZE));
  float4 a = *(const float4*)(src);
  float4 b = *(const float4*)(src + 4);
  u16x8 o;
  o[0] = f2h_bits(a.x); o[1] = f2h_bits(a.y);
  o[2] = f2h_bits(a.z); o[3] = f2h_bits(a.w);
  o[4] = f2h_bits(b.x); o[5] = f2h_bits(b.y);
  o[6] = f2h_bits(b.z); o[7] = f2h_bits(b.w);
  *(u16x8*)(xh + i) = o;
}

// ---------------- kernel 2: W [K][N] fp32 -> Wt [N][K] fp16 ----------------
__global__ __launch_bounds__(256) void wtrans(
    const float* __restrict__ w0, const float* __restrict__ w1,
    const float* __restrict__ w2, const float* __restrict__ w3,
    const float* __restrict__ w4, const float* __restrict__ w5,
    u16* __restrict__ wt) {
  __shared__ float tile[32][33];
  const int z = blockIdx.z;
  const float* W = z == 0 ? w0 : z == 1 ? w1 : z == 2 ? w2
                 : z == 3 ? w3 : z == 4 ? w4 : w5;
  u16* WT = wt + (size_t)z * 262144u;
  const int k0 = blockIdx.x * 32, n0 = blockIdx.y * 32;
  const int tx = threadIdx.x, ty = threadIdx.y;  // 32 x 8
  for (int j = 0; j < 32; j += 8)
    tile[ty + j][tx] = W[(size_t)(k0 + ty + j) * 512 + n0 + tx];
  __syncthreads();
  for (int j = 0; j < 32; j += 8)
    WT[(size_t)(n0 + ty + j) * 512 + k0 + tx] = f2h_bits(tile[tx][ty + j]);
}

// ---------------- kernel 3: six projections, C = X*W + b -------------------
// R9 form (passed at 474.5us). Proj ledger closed: dbuf (R7), cst-epilogue
// (R8), occupancy 3/CU (R9) all neutral; input-blob (R10) failed replay
// determinism. Keep as-is.
// Blob layouts (consumed linearly by attn staging):
//  K blob: per b, per 32-key tile kt: slot p = dchunk*32+key holds
//          K[key][dchunk*8 .. +8).
//  V blob: per b, per tile kt: slot p = kc*512 + d holds
//          V[token kt*32+kc*8 .. +8)[d].
__global__ __launch_bounds__(256, 3) void proj_gemm(
    const u16* __restrict__ xh, const u16* __restrict__ wt,
    u16* __restrict__ qkv,
    const float* __restrict__ b0, const float* __restrict__ b1,
    const float* __restrict__ b2, const float* __restrict__ b3,
    const float* __restrict__ b4, const float* __restrict__ b5) {
  const int proj = blockIdx.z;
  const u16* X = xh + (proj < 3 ? 0u : SZE);
  const u16* W = wt + (size_t)proj * 262144u;
  u16* out = qkv + (size_t)proj * SZE;
  const float* bias = proj == 0 ? b0 : proj == 1 ? b1 : proj == 2 ? b2
                    : proj == 3 ? b3 : proj == 4 ? b4 : b5;
  const int m0 = blockIdx.x * 128, n0 = blockIdx.y * 128;
  const int t = threadIdx.x, lane = t & 63, w = t >> 6;
  const int wr = w >> 1, wc = w & 1, ml = lane & 15, q = lane >> 4;
  __shared__ u16 sA[2][4096], sB[2][4096];
  fx4 acc[4][4] = {};
  // prologue: stage k-tile 0 into buffer 0
  for (int r = 0; r < 2; ++r) {
    int ci = r * 256 + t;
    int cq = ci >> 7, cm = ci & 127;
    gl2lds16(X + (size_t)(m0 + cm) * 512 + cq * 8, sA[0] + ci * 8);
    gl2lds16(W + (size_t)(n0 + cm) * 512 + cq * 8, sB[0] + ci * 8);
  }
  __syncthreads();
  for (int kt = 0; kt < 16; ++kt) {
    const int c = kt & 1;
    if (kt < 15) {
      const int k0 = (kt + 1) * 32;
      for (int r = 0; r < 2; ++r) {
        int ci = r * 256 + t;
        int cq = ci >> 7, cm = ci & 127;
        gl2lds16(X + (size_t)(m0 + cm) * 512 + (k0 + cq * 8), sA[c ^ 1] + ci * 8);
        gl2lds16(W + (size_t)(n0 + cm) * 512 + (k0 + cq * 8), sB[c ^ 1] + ci * 8);
      }
    }
    f16x8 af[4], bf[4];
    for (int i = 0; i < 4; ++i) {
      af[i] = *(const f16x8*)(sA[c] + (q * 128 + wr * 64 + i * 16 + ml) * 8);
      bf[i] = *(const f16x8*)(sB[c] + (q * 128 + wc * 64 + i * 16 + ml) * 8);
    }
    for (int i = 0; i < 4; ++i)
      for (int j = 0; j < 4; ++j)
        acc[i][j] = __builtin_amdgcn_mfma_f32_16x16x32_f16(af[i], bf[j],
                                                           acc[i][j], 0, 0, 0);
    __syncthreads();
  }
  const int pm = proj % 3;  // 0=Q (row-major), 1=K blob, 2=V blob
  for (int j = 0; j < 4; ++j) {
    const int n = n0 + wc * 64 + j * 16 + ml;
    const float bv = bias[n];
    for (int i = 0; i < 4; ++i) {
      const int mb = m0 + wr * 64 + i * 16 + q * 4;
      if (pm == 0) {
        for (int r = 0; r < 4; ++r)
          out[(size_t)(mb + r) * 512 + n] = f2h_bits(acc[i][j][r] + bv);
      } else if (pm == 1) {
        for (int r = 0; r < 4; ++r) {
          const int m = mb + r, kq = m & 2047;
          size_t a = (size_t)(m >> 11) * 1048576u + (size_t)(kq >> 5) * 16384u
                   + (size_t)((n >> 3) * 32 + (kq & 31)) * 8u + (size_t)(n & 7);
          out[a] = f2h_bits(acc[i][j][r] + bv);
        }
      } else {
        const int l = mb & 2047;
        size_t a = (size_t)(mb >> 11) * 1048576u + (size_t)(l >> 5) * 16384u
                 + (size_t)(((l & 31) >> 3) * 512 + n) * 8u + (size_t)(l & 7);
        u16x4 pk;
        for (int r = 0; r < 4; ++r) pk[r] = f2h_bits(acc[i][j][r] + bv);
        *(u16x4*)(out + a) = pk;
      }
    }
  }
}

// ---------------- kernel 4: flash cross-attention v14 ----------------------
// R12 (tile-blob staging + setprio, ~234us) + ONE isolated change: the two
// 16-lane __shfl_xor butterfly reduces become DPP VALU reduces. Post-v11 the
// LDS pipe is the dominant attn resource (~5800 of 8900 cyc/iter/CU); the
// 256 ds_bpermute ops/CU/iter behind __shfl_xor are ~1500 of those cycles
// and sit on a 4-deep serial chain. DPP moves them to the VALU pipe at ~1/3
// the latency. Everything else byte-identical (softmax stays straight-line;
// v12's branchy defer-max is NOT included).
__global__ __launch_bounds__(512, 2) void attn_kernel(const u16* __restrict__ qkv,
                                                      float* __restrict__ out) {
  const int t = threadIdx.x, lane = t & 63, w = t >> 6;  // w in 0..7
  const int ml = lane & 15, q = lane >> 4;
  // XCD swizzle: xcd = n&7 owns (b,tt) groups {2*xcd, 2*xcd+1}
  const int n = blockIdx.x;
  const int xcd = n & 7, slot = n >> 3;
  const int g = xcd * 2 + (slot >> 4);
  const int qt = slot & 15;
  const int b = g >> 1, tt = g & 1;

  const u16* Q  = qkv + (tt ? (size_t)3 * SZE : (size_t)0);
  const u16* K  = qkv + (tt ? (size_t)1 * SZE : (size_t)4 * SZE);
  const u16* Vt = qkv + (tt ? (size_t)5 * SZE : (size_t)2 * SZE);
  float* O = out + (tt ? (size_t)SZE : (size_t)0) +
             ((size_t)b * 2048 + qt * 128) * 512;
  const u16* Qb = Q + ((size_t)b * 2048 + qt * 128) * 512;
  const u16* Kb = K + (size_t)b * 1048576u;   // blob: [kt(64)][16384]
  const u16* Vb = Vt + (size_t)b * 1048576u;  // blob: [kt(64)][16384]

  __shared__ u16 sK[2][16384];   // 2 x 32KB, slot p: [dchunk(64)][key(32)]
  __shared__ u16 sV[2][16384];   // 2 x 32KB, slot p: [kc(4)][d(512)]
  __shared__ u16 sP[8 * 640];    // per-wave 16 rows x stride 40

  // Q A-frags for this wave's 16 rows (64 VGPR, resident all 64 iters)
  f16x8 qf[16];
  {
    const u16* qrow = Qb + (size_t)(w * 16 + ml) * 512 + q * 8;
#pragma unroll
    for (int ks = 0; ks < 16; ++ks) qf[ks] = *(const f16x8*)(qrow + ks * 32);
  }

  fx4 acc[32] = {};  // rows q*4+r (of wave's 16), col nj*16+ml  (128 VGPR)
  fx4 mrun = {-3.0e38f, -3.0e38f, -3.0e38f, -3.0e38f};
  fx4 lrun = {0.f, 0.f, 0.f, 0.f};
  u16* wp = sP + w * 640;

  // prestage tile 0 (linear: lane-consecutive 16B, fully coalesced)
#pragma unroll
  for (int r = 0; r < 4; ++r) {
    int p = r * 512 + t;
    gl2lds16(Kb + (size_t)p * 8, sK[0] + p * 8);
    gl2lds16(Vb + (size_t)p * 8, sV[0] + p * 8);
  }
  __syncthreads();

  for (int it = 0; it < 64; ++it) {
    const int c = it & 1;
    const u16* sKc = sK[c];
    const u16* sVc = sV[c];
    // ---- stage tile it+1 (linear blob reads); drained at end barrier ----
    if (it < 63) {
      const u16* Kn = Kb + (size_t)(it + 1) * 16384u;
      const u16* Vn = Vb + (size_t)(it + 1) * 16384u;
#pragma unroll
      for (int r = 0; r < 4; ++r) {
        int p = r * 512 + t;
        gl2lds16(Kn + (size_t)p * 8, sK[c ^ 1] + p * 8);
        gl2lds16(Vn + (size_t)p * 8, sV[c ^ 1] + p * 8);
      }
    }
    // ---- QK^T: this wave's 16 rows x 32 keys ----
    fx4 s0 = {0.f, 0.f, 0.f, 0.f}, s1 = {0.f, 0.f, 0.f, 0.f};
    __builtin_amdgcn_s_setprio(1);
#pragma unroll
    for (int ks = 0; ks < 16; ++ks) {
      f16x8 kf0 = *(const f16x8*)(sKc + ((ks * 4 + q) * 32 + ml) * 8);
      f16x8 kf1 = *(const f16x8*)(sKc + ((ks * 4 + q) * 32 + 16 + ml) * 8);
      s0 = __builtin_amdgcn_mfma_f32_16x16x32_f16(qf[ks], kf0, s0, 0, 0, 0);
      s1 = __builtin_amdgcn_mfma_f32_16x16x32_f16(qf[ks], kf1, s1, 0, 0, 0);
    }
    __builtin_amdgcn_s_setprio(0);
    // ---- online softmax, state in regs; DPP reduces (VALU pipe) ----
    fx4 mx, alpha, p0, p1, sm;
#pragma unroll
    for (int r = 0; r < 4; ++r) mx[r] = rowmax16(fmaxf(s0[r], s1[r]));
    bool need = false;
#pragma unroll
    for (int r = 0; r < 4; ++r) {
      float mn = fmaxf(mrun[r], mx[r]);
      alpha[r] = __expf(mrun[r] - mn);
      mrun[r] = mn;
      p0[r] = __expf(s0[r] - mn);
      p1[r] = __expf(s1[r] - mn);
      need |= (alpha[r] != 1.0f);
    }
#pragma unroll
    for (int r = 0; r < 4; ++r) sm[r] = rowsum16(p0[r] + p1[r]);
#pragma unroll
    for (int r = 0; r < 4; ++r) lrun[r] = alpha[r] * lrun[r] + sm[r];
    // ---- P -> wave-private slab (no barrier: same-wave lgkm ordering) ----
#pragma unroll
    for (int r = 0; r < 4; ++r) {
      wp[(q * 4 + r) * 40 + ml] = f2h_bits(p0[r]);
      wp[(q * 4 + r) * 40 + 16 + ml] = f2h_bits(p1[r]);
    }
    // ---- rescale acc (skip when no row saw a new max) ----
    if (__any(need)) {
#pragma unroll
      for (int nj = 0; nj < 32; ++nj) {
        acc[nj][0] *= alpha[0]; acc[nj][1] *= alpha[1];
        acc[nj][2] *= alpha[2]; acc[nj][3] *= alpha[3];
      }
    }
    f16x8 pf = *(const f16x8*)(wp + ml * 40 + q * 8);
    // ---- PV over all 512 d (one shared pf) ----
    __builtin_amdgcn_s_setprio(1);
#pragma unroll
    for (int nj = 0; nj < 32; ++nj) {
      f16x8 vf = *(const f16x8*)(sVc + (q * 512 + nj * 16 + ml) * 8);
      acc[nj] = __builtin_amdgcn_mfma_f32_16x16x32_f16(pf, vf, acc[nj], 0, 0, 0);
    }
    __builtin_amdgcn_s_setprio(0);
    __syncthreads();  // single barrier: drains next-iter staging + buffer flip
  }
  // ---- epilogue: O = acc / l (all wave-private) ----
  fx4 linv;
#pragma unroll
  for (int r = 0; r < 4; ++r) linv[r] = 1.0f / lrun[r];
  float* Ob = O + (size_t)(w * 16 + q * 4) * 512 + ml;
#pragma unroll
  for (int nj = 0; nj < 32; ++nj) {
#pragma unroll
    for (int r = 0; r < 4; ++r)
      Ob[(size_t)r * 512 + nj * 16] = acc[nj][r] * linv[r];
  }
}

extern "C" void kernel_launch(void* const* d_in, const int* in_sizes, int n_in,
                              void* d_out, int out_size, void* d_ws, size_t ws_size,
                              hipStream_t stream) {
  // ws layout (u16 elems): [xh: 2*SZE][wt: 6*512*512][qkv: 6*SZE]
  //   qkv order: 0=Qr 1=Kr(blob) 2=Vr^T(blob) 3=Qh 4=Kh(blob) 5=Vh^T(blob)
  u16* ws = (u16*)d_ws;
  u16* xh = ws;
  u16* wt = ws + 16777216u;            // 2*SZE
  u16* qkv = ws + 18350080u;           // 2*SZE + 6*262144

  convert_x<<<8192, 256, 0, stream>>>((const float*)d_in[0],
                                      (const float*)d_in[1], xh);
  wtrans<<<dim3(16, 16, 6), dim3(32, 8), 0, stream>>>(
      (const float*)d_in[2], (const float*)d_in[4], (const float*)d_in[6],
      (const float*)d_in[8], (const float*)d_in[10], (const float*)d_in[12], wt);
  proj_gemm<<<dim3(128, 4, 6), 256, 0, stream>>>(
      xh, wt, qkv,
      (const float*)d_in[3], (const float*)d_in[5], (const float*)d_in[7],
      (const float*)d_in[9], (const float*)d_in[11], (const float*)d_in[13]);
  attn_kernel<<<256, 512, 0, stream>>>(qkv, (float*)d_out);
}

// Round 15
// 460.612 us; speedup vs baseline: 1.0369x; 1.0070x over previous
//
#include <hip/hip_runtime.h>

typedef unsigned short u16;
typedef _Float16 f16;
typedef __attribute__((ext_vector_type(8))) f16 f16x8;
typedef __attribute__((ext_vector_type(4))) float fx4;
typedef __attribute__((ext_vector_type(8))) u16 u16x8;
typedef __attribute__((ext_vector_type(4))) u16 u16x4;

#define SZE 8388608u  // 16384*512 elements per [B*L, D] matrix

__device__ __forceinline__ u16 f2h_bits(float x) {
  union { f16 h; u16 u; } v; v.h = (f16)x; return v.u;
}

// async global->LDS, 16B per lane; dest is wave-uniform base + lane*16.
__device__ __forceinline__ void gl2lds16(const void* g, void* l) {
  __builtin_amdgcn_global_load_lds(
      (const __attribute__((address_space(1))) unsigned int*)g,
      (__attribute__((address_space(3))) unsigned int*)l, 16, 0, 0);
}

// ---- DPP 16-lane all-reduce (VALU-only; replaces ds_bpermute shfl chains).
// Reduce domain = 16 contiguous lanes (q*16..q*16+15) = one DPP row.
// quad_perm[1,0,3,2]=0xB1 (xor1), quad_perm[2,3,0,1]=0x4E (xor2); after
// those values are quad-uniform, so row_half_mirror(0x141) acts as xor4 and
// row_mirror(0x140) as xor8. Measured R13: attn 234->216us, MfmaUtil 24.7->28.
template <int C>
__device__ __forceinline__ float dppf(float x) {
  return __int_as_float(__builtin_amdgcn_update_dpp(
      __float_as_int(x), __float_as_int(x), C, 0xf, 0xf, false));
}
__device__ __forceinline__ float rowmax16(float x) {
  x = fmaxf(x, dppf<0xB1>(x));
  x = fmaxf(x, dppf<0x4E>(x));
  x = fmaxf(x, dppf<0x141>(x));
  x = fmaxf(x, dppf<0x140>(x));
  return x;
}
__device__ __forceinline__ float rowsum16(float x) {
  x += dppf<0xB1>(x);
  x += dppf<0x4E>(x);
  x += dppf<0x141>(x);
  x += dppf<0x140>(x);
  return x;
}

// ---------------- kernel 1: fp32 -> fp16 convert of both inputs ------------
// Row-major output. NOTE (session ledger): writing xh in proj's blob order
// (R10/R14) gains ~20us in proj but FAILS graph-replay determinism with an
// unlocalized race in the scattered-write -> global_load_lds-read path.
// Do not re-attempt without a way to localize it (disasm + replay loop).
__global__ __launch_bounds__(256) void convert_x(const float* __restrict__ x0,
                                                 const float* __restrict__ x1,
                                                 u16* __restrict__ xh) {
  size_t i = ((size_t)blockIdx.x * 256 + threadIdx.x) * 8;
  const float* src = (i < SZE) ? (x0 + i) : (x1 + (i - SZE));
  float4 a = *(const float4*)(src);
  float4 b = *(const float4*)(src + 4);
  u16x8 o;
  o[0] = f2h_bits(a.x); o[1] = f2h_bits(a.y);
  o[2] = f2h_bits(a.z); o[3] = f2h_bits(a.w);
  o[4] = f2h_bits(b.x); o[5] = f2h_bits(b.y);
  o[6] = f2h_bits(b.z); o[7] = f2h_bits(b.w);
  *(u16x8*)(xh + i) = o;
}

// ---------------- kernel 2: W [K][N] fp32 -> Wt [N][K] fp16 ----------------
__global__ __launch_bounds__(256) void wtrans(
    const float* __restrict__ w0, const float* __restrict__ w1,
    const float* __restrict__ w2, const float* __restrict__ w3,
    const float* __restrict__ w4, const float* __restrict__ w5,
    u16* __restrict__ wt) {
  __shared__ float tile[32][33];
  const int z = blockIdx.z;
  const float* W = z == 0 ? w0 : z == 1 ? w1 : z == 2 ? w2
                 : z == 3 ? w3 : z == 4 ? w4 : w5;
  u16* WT = wt + (size_t)z * 262144u;
  const int k0 = blockIdx.x * 32, n0 = blockIdx.y * 32;
  const int tx = threadIdx.x, ty = threadIdx.y;  // 32 x 8
  for (int j = 0; j < 32; j += 8)
    tile[ty + j][tx] = W[(size_t)(k0 + ty + j) * 512 + n0 + tx];
  __syncthreads();
  for (int j = 0; j < 32; j += 8)
    WT[(size_t)(n0 + ty + j) * 512 + k0 + tx] = f2h_bits(tile[tx][ty + j]);
}

// ---------------- kernel 3: six projections, C = X*W + b -------------------
// R9 form. Proj ledger closed: dbuf (R7), cst-epilogue (R8), occupancy 3/CU
// (R9) all neutral; input-blob (R10 both-sides, R14 X-side) real ~20-25us
// gain but fails replay determinism. Keep as-is.
// Output blob layouts (consumed linearly by attn staging):
//  K blob: per b, per 32-key tile kt: slot p = dchunk*32+key holds
//          K[key][dchunk*8 .. +8).
//  V blob: per b, per tile kt: slot p = kc*512 + d holds
//          V[token kt*32+kc*8 .. +8)[d].
__global__ __launch_bounds__(256, 3) void proj_gemm(
    const u16* __restrict__ xh, const u16* __restrict__ wt,
    u16* __restrict__ qkv,
    const float* __restrict__ b0, const float* __restrict__ b1,
    const float* __restrict__ b2, const float* __restrict__ b3,
    const float* __restrict__ b4, const float* __restrict__ b5) {
  const int proj = blockIdx.z;
  const u16* X = xh + (proj < 3 ? 0u : SZE);
  const u16* W = wt + (size_t)proj * 262144u;
  u16* out = qkv + (size_t)proj * SZE;
  const float* bias = proj == 0 ? b0 : proj == 1 ? b1 : proj == 2 ? b2
                    : proj == 3 ? b3 : proj == 4 ? b4 : b5;
  const int m0 = blockIdx.x * 128, n0 = blockIdx.y * 128;
  const int t = threadIdx.x, lane = t & 63, w = t >> 6;
  const int wr = w >> 1, wc = w & 1, ml = lane & 15, q = lane >> 4;
  __shared__ u16 sA[2][4096], sB[2][4096];
  fx4 acc[4][4] = {};
  // prologue: stage k-tile 0 into buffer 0
  for (int r = 0; r < 2; ++r) {
    int ci = r * 256 + t;
    int cq = ci >> 7, cm = ci & 127;
    gl2lds16(X + (size_t)(m0 + cm) * 512 + cq * 8, sA[0] + ci * 8);
    gl2lds16(W + (size_t)(n0 + cm) * 512 + cq * 8, sB[0] + ci * 8);
  }
  __syncthreads();
  for (int kt = 0; kt < 16; ++kt) {
    const int c = kt & 1;
    if (kt < 15) {
      const int k0 = (kt + 1) * 32;
      for (int r = 0; r < 2; ++r) {
        int ci = r * 256 + t;
        int cq = ci >> 7, cm = ci & 127;
        gl2lds16(X + (size_t)(m0 + cm) * 512 + (k0 + cq * 8), sA[c ^ 1] + ci * 8);
        gl2lds16(W + (size_t)(n0 + cm) * 512 + (k0 + cq * 8), sB[c ^ 1] + ci * 8);
      }
    }
    f16x8 af[4], bf[4];
    for (int i = 0; i < 4; ++i) {
      af[i] = *(const f16x8*)(sA[c] + (q * 128 + wr * 64 + i * 16 + ml) * 8);
      bf[i] = *(const f16x8*)(sB[c] + (q * 128 + wc * 64 + i * 16 + ml) * 8);
    }
    for (int i = 0; i < 4; ++i)
      for (int j = 0; j < 4; ++j)
        acc[i][j] = __builtin_amdgcn_mfma_f32_16x16x32_f16(af[i], bf[j],
                                                           acc[i][j], 0, 0, 0);
    __syncthreads();
  }
  const int pm = proj % 3;  // 0=Q (row-major), 1=K blob, 2=V blob
  for (int j = 0; j < 4; ++j) {
    const int n = n0 + wc * 64 + j * 16 + ml;
    const float bv = bias[n];
    for (int i = 0; i < 4; ++i) {
      const int mb = m0 + wr * 64 + i * 16 + q * 4;
      if (pm == 0) {
        for (int r = 0; r < 4; ++r)
          out[(size_t)(mb + r) * 512 + n] = f2h_bits(acc[i][j][r] + bv);
      } else if (pm == 1) {
        for (int r = 0; r < 4; ++r) {
          const int m = mb + r, kq = m & 2047;
          size_t a = (size_t)(m >> 11) * 1048576u + (size_t)(kq >> 5) * 16384u
                   + (size_t)((n >> 3) * 32 + (kq & 31)) * 8u + (size_t)(n & 7);
          out[a] = f2h_bits(acc[i][j][r] + bv);
        }
      } else {
        const int l = mb & 2047;
        size_t a = (size_t)(mb >> 11) * 1048576u + (size_t)(l >> 5) * 16384u
                 + (size_t)(((l & 31) >> 3) * 512 + n) * 8u + (size_t)(l & 7);
        u16x4 pk;
        for (int r = 0; r < 4; ++r) pk[r] = f2h_bits(acc[i][j][r] + bv);
        *(u16x4*)(out + a) = pk;
      }
    }
  }
}

// ---------------- kernel 4: flash cross-attention v14 (proven, 216us) ------
// Tile-blob staging + setprio + DPP softmax reduces. Straight-line softmax;
// no control-flow-dependent live state around acc (v12 spill lesson).
__global__ __launch_bounds__(512, 2) void attn_kernel(const u16* __restrict__ qkv,
                                                      float* __restrict__ out) {
  const int t = threadIdx.x, lane = t & 63, w = t >> 6;  // w in 0..7
  const int ml = lane & 15, q = lane >> 4;
  // XCD swizzle: xcd = n&7 owns (b,tt) groups {2*xcd, 2*xcd+1}
  const int n = blockIdx.x;
  const int xcd = n & 7, slot = n >> 3;
  const int g = xcd * 2 + (slot >> 4);
  const int qt = slot & 15;
  const int b = g >> 1, tt = g & 1;

  const u16* Q  = qkv + (tt ? (size_t)3 * SZE : (size_t)0);
  const u16* K  = qkv + (tt ? (size_t)1 * SZE : (size_t)4 * SZE);
  const u16* Vt = qkv + (tt ? (size_t)5 * SZE : (size_t)2 * SZE);
  float* O = out + (tt ? (size_t)SZE : (size_t)0) +
             ((size_t)b * 2048 + qt * 128) * 512;
  const u16* Qb = Q + ((size_t)b * 2048 + qt * 128) * 512;
  const u16* Kb = K + (size_t)b * 1048576u;   // blob: [kt(64)][16384]
  const u16* Vb = Vt + (size_t)b * 1048576u;  // blob: [kt(64)][16384]

  __shared__ u16 sK[2][16384];   // 2 x 32KB, slot p: [dchunk(64)][key(32)]
  __shared__ u16 sV[2][16384];   // 2 x 32KB, slot p: [kc(4)][d(512)]
  __shared__ u16 sP[8 * 640];    // per-wave 16 rows x stride 40

  // Q A-frags for this wave's 16 rows (64 VGPR, resident all 64 iters)
  f16x8 qf[16];
  {
    const u16* qrow = Qb + (size_t)(w * 16 + ml) * 512 + q * 8;
#pragma unroll
    for (int ks = 0; ks < 16; ++ks) qf[ks] = *(const f16x8*)(qrow + ks * 32);
  }

  fx4 acc[32] = {};  // rows q*4+r (of wave's 16), col nj*16+ml  (128 VGPR)
  fx4 mrun = {-3.0e38f, -3.0e38f, -3.0e38f, -3.0e38f};
  fx4 lrun = {0.f, 0.f, 0.f, 0.f};
  u16* wp = sP + w * 640;

  // prestage tile 0 (linear: lane-consecutive 16B, fully coalesced)
#pragma unroll
  for (int r = 0; r < 4; ++r) {
    int p = r * 512 + t;
    gl2lds16(Kb + (size_t)p * 8, sK[0] + p * 8);
    gl2lds16(Vb + (size_t)p * 8, sV[0] + p * 8);
  }
  __syncthreads();

  for (int it = 0; it < 64; ++it) {
    const int c = it & 1;
    const u16* sKc = sK[c];
    const u16* sVc = sV[c];
    // ---- stage tile it+1 (linear blob reads); drained at end barrier ----
    if (it < 63) {
      const u16* Kn = Kb + (size_t)(it + 1) * 16384u;
      const u16* Vn = Vb + (size_t)(it + 1) * 16384u;
#pragma unroll
      for (int r = 0; r < 4; ++r) {
        int p = r * 512 + t;
        gl2lds16(Kn + (size_t)p * 8, sK[c ^ 1] + p * 8);
        gl2lds16(Vn + (size_t)p * 8, sV[c ^ 1] + p * 8);
      }
    }
    // ---- QK^T: this wave's 16 rows x 32 keys ----
    fx4 s0 = {0.f, 0.f, 0.f, 0.f}, s1 = {0.f, 0.f, 0.f, 0.f};
    __builtin_amdgcn_s_setprio(1);
#pragma unroll
    for (int ks = 0; ks < 16; ++ks) {
      f16x8 kf0 = *(const f16x8*)(sKc + ((ks * 4 + q) * 32 + ml) * 8);
      f16x8 kf1 = *(const f16x8*)(sKc + ((ks * 4 + q) * 32 + 16 + ml) * 8);
      s0 = __builtin_amdgcn_mfma_f32_16x16x32_f16(qf[ks], kf0, s0, 0, 0, 0);
      s1 = __builtin_amdgcn_mfma_f32_16x16x32_f16(qf[ks], kf1, s1, 0, 0, 0);
    }
    __builtin_amdgcn_s_setprio(0);
    // ---- online softmax, state in regs; DPP reduces (VALU pipe) ----
    fx4 mx, alpha, p0, p1, sm;
#pragma unroll
    for (int r = 0; r < 4; ++r) mx[r] = rowmax16(fmaxf(s0[r], s1[r]));
    bool need = false;
#pragma unroll
    for (int r = 0; r < 4; ++r) {
      float mn = fmaxf(mrun[r], mx[r]);
      alpha[r] = __expf(mrun[r] - mn);
      mrun[r] = mn;
      p0[r] = __expf(s0[r] - mn);
      p1[r] = __expf(s1[r] - mn);
      need |= (alpha[r] != 1.0f);
    }
#pragma unroll
    for (int r = 0; r < 4; ++r) sm[r] = rowsum16(p0[r] + p1[r]);
#pragma unroll
    for (int r = 0; r < 4; ++r) lrun[r] = alpha[r] * lrun[r] + sm[r];
    // ---- P -> wave-private slab (no barrier: same-wave lgkm ordering) ----
#pragma unroll
    for (int r = 0; r < 4; ++r) {
      wp[(q * 4 + r) * 40 + ml] = f2h_bits(p0[r]);
      wp[(q * 4 + r) * 40 + 16 + ml] = f2h_bits(p1[r]);
    }
    // ---- rescale acc (skip when no row saw a new max) ----
    if (__any(need)) {
#pragma unroll
      for (int nj = 0; nj < 32; ++nj) {
        acc[nj][0] *= alpha[0]; acc[nj][1] *= alpha[1];
        acc[nj][2] *= alpha[2]; acc[nj][3] *= alpha[3];
      }
    }
    f16x8 pf = *(const f16x8*)(wp + ml * 40 + q * 8);
    // ---- PV over all 512 d (one shared pf) ----
    __builtin_amdgcn_s_setprio(1);
#pragma unroll
    for (int nj = 0; nj < 32; ++nj) {
      f16x8 vf = *(const f16x8*)(sVc + (q * 512 + nj * 16 + ml) * 8);
      acc[nj] = __builtin_amdgcn_mfma_f32_16x16x32_f16(pf, vf, acc[nj], 0, 0, 0);
    }
    __builtin_amdgcn_s_setprio(0);
    __syncthreads();  // single barrier: drains next-iter staging + buffer flip
  }
  // ---- epilogue: O = acc / l (all wave-private) ----
  fx4 linv;
#pragma unroll
  for (int r = 0; r < 4; ++r) linv[r] = 1.0f / lrun[r];
  float* Ob = O + (size_t)(w * 16 + q * 4) * 512 + ml;
#pragma unroll
  for (int nj = 0; nj < 32; ++nj) {
#pragma unroll
    for (int r = 0; r < 4; ++r)
      Ob[(size_t)r * 512 + nj * 16] = acc[nj][r] * linv[r];
  }
}

extern "C" void kernel_launch(void* const* d_in, const int* in_sizes, int n_in,
                              void* d_out, int out_size, void* d_ws, size_t ws_size,
                              hipStream_t stream) {
  // ws layout (u16 elems): [xh: 2*SZE][wt: 6*512*512][qkv: 6*SZE]
  //   qkv order: 0=Qr 1=Kr(blob) 2=Vr^T(blob) 3=Qh 4=Kh(blob) 5=Vh^T(blob)
  u16* ws = (u16*)d_ws;
  u16* xh = ws;
  u16* wt = ws + 16777216u;            // 2*SZE
  u16* qkv = ws + 18350080u;           // 2*SZE + 6*262144

  convert_x<<<8192, 256, 0, stream>>>((const float*)d_in[0],
                                      (const float*)d_in[1], xh);
  wtrans<<<dim3(16, 16, 6), dim3(32, 8), 0, stream>>>(
      (const float*)d_in[2], (const float*)d_in[4], (const float*)d_in[6],
      (const float*)d_in[8], (const float*)d_in[10], (const float*)d_in[12], wt);
  proj_gemm<<<dim3(128, 4, 6), 256, 0, stream>>>(
      xh, wt, qkv,
      (const float*)d_in[3], (const float*)d_in[5], (const float*)d_in[7],
      (const float*)d_in[9], (const float*)d_in[11], (const float*)d_in[13]);
  attn_kernel<<<256, 512, 0, stream>>>(qkv, (float*)d_out);
}

// Round 16
// 423.776 us; speedup vs baseline: 1.1270x; 1.0869x over previous
//
#include <hip/hip_runtime.h>

typedef unsigned short u16;
typedef _Float16 f16;
typedef __attribute__((ext_vector_type(8))) f16 f16x8;
typedef __attribute__((ext_vector_type(4))) float fx4;
typedef __attribute__((ext_vector_type(8))) u16 u16x8;
typedef __attribute__((ext_vector_type(4))) u16 u16x4;

#define SZE 8388608u  // 16384*512 elements per [B*L, D] matrix

__device__ __forceinline__ u16 f2h_bits(float x) {
  union { f16 h; u16 u; } v; v.h = (f16)x; return v.u;
}

// async global->LDS, 16B per lane; dest is wave-uniform base + lane*16.
__device__ __forceinline__ void gl2lds16(const void* g, void* l) {
  __builtin_amdgcn_global_load_lds(
      (const __attribute__((address_space(1))) unsigned int*)g,
      (__attribute__((address_space(3))) unsigned int*)l, 16, 0, 0);
}

// ---- DPP 16-lane all-reduce (VALU-only; replaces ds_bpermute shfl chains).
// Reduce domain = 16 contiguous lanes (q*16..q*16+15) = one DPP row.
// quad_perm[1,0,3,2]=0xB1 (xor1), quad_perm[2,3,0,1]=0x4E (xor2); after
// those values are quad-uniform, so row_half_mirror(0x141) acts as xor4 and
// row_mirror(0x140) as xor8. Measured R13: attn 234->216us, MfmaUtil 24.7->28.
template <int C>
__device__ __forceinline__ float dppf(float x) {
  return __int_as_float(__builtin_amdgcn_update_dpp(
      __float_as_int(x), __float_as_int(x), C, 0xf, 0xf, false));
}
__device__ __forceinline__ float rowmax16(float x) {
  x = fmaxf(x, dppf<0xB1>(x));
  x = fmaxf(x, dppf<0x4E>(x));
  x = fmaxf(x, dppf<0x141>(x));
  x = fmaxf(x, dppf<0x140>(x));
  return x;
}
__device__ __forceinline__ float rowsum16(float x) {
  x += dppf<0xB1>(x);
  x += dppf<0x4E>(x);
  x += dppf<0x141>(x);
  x += dppf<0x140>(x);
  return x;
}

// ---------------- kernel 1: fp32 -> fp16 convert of both inputs ------------
// Row-major output (unchanged). Session ledger: producer-side blob layouts
// (R10/R14) gain ~20us in proj but fail graph-replay determinism -- the fix
// this round is READ-side only, inside proj_gemm.
__global__ __launch_bounds__(256) void convert_x(const float* __restrict__ x0,
                                                 const float* __restrict__ x1,
                                                 u16* __restrict__ xh) {
  size_t i = ((size_t)blockIdx.x * 256 + threadIdx.x) * 8;
  const float* src = (i < SZE) ? (x0 + i) : (x1 + (i - SZE));
  float4 a = *(const float4*)(src);
  float4 b = *(const float4*)(src + 4);
  u16x8 o;
  o[0] = f2h_bits(a.x); o[1] = f2h_bits(a.y);
  o[2] = f2h_bits(a.z); o[3] = f2h_bits(a.w);
  o[4] = f2h_bits(b.x); o[5] = f2h_bits(b.y);
  o[6] = f2h_bits(b.z); o[7] = f2h_bits(b.w);
  *(u16x8*)(xh + i) = o;
}

// ---------------- kernel 2: W [K][N] fp32 -> Wt [N][K] fp16 ----------------
__global__ __launch_bounds__(256) void wtrans(
    const float* __restrict__ w0, const float* __restrict__ w1,
    const float* __restrict__ w2, const float* __restrict__ w3,
    const float* __restrict__ w4, const float* __restrict__ w5,
    u16* __restrict__ wt) {
  __shared__ float tile[32][33];
  const int z = blockIdx.z;
  const float* W = z == 0 ? w0 : z == 1 ? w1 : z == 2 ? w2
                 : z == 3 ? w3 : z == 4 ? w4 : w5;
  u16* WT = wt + (size_t)z * 262144u;
  const int k0 = blockIdx.x * 32, n0 = blockIdx.y * 32;
  const int tx = threadIdx.x, ty = threadIdx.y;  // 32 x 8
  for (int j = 0; j < 32; j += 8)
    tile[ty + j][tx] = W[(size_t)(k0 + ty + j) * 512 + n0 + tx];
  __syncthreads();
  for (int j = 0; j < 32; j += 8)
    WT[(size_t)(n0 + ty + j) * 512 + k0 + tx] = f2h_bits(tile[tx][ty + j]);
}

// ---------------- kernel 3: six projections, C = X*W + b -------------------
// DENSE-STAGING ROUND (read-side fix of the R10/R14 defect, zero race
// surface): staging lane ci now reads (row=ci>>2, kchunk=ci&3) -- lanes 0-3
// read one row's contiguous 64B = ONE cache line coalesced in-instruction
// (vs 64 distinct lines per wave before: 4x fewer L2 line-requests, the
// resource R10/R14 proved is worth ~20-25us). The linear gl2lds16 dest then
// yields a row-major [128][32] LDS tile; fragment reads use slot row*4+q
// (still conflict-free: 64 lanes cover 1KB contiguous, permuted).
// Producers and all writes unchanged.
// Output blob layouts (consumed linearly by attn staging):
//  K blob: per b, per 32-key tile kt: slot p = dchunk*32+key holds
//          K[key][dchunk*8 .. +8).
//  V blob: per b, per tile kt: slot p = kc*512 + d holds
//          V[token kt*32+kc*8 .. +8)[d].
__global__ __launch_bounds__(256, 3) void proj_gemm(
    const u16* __restrict__ xh, const u16* __restrict__ wt,
    u16* __restrict__ qkv,
    const float* __restrict__ b0, const float* __restrict__ b1,
    const float* __restrict__ b2, const float* __restrict__ b3,
    const float* __restrict__ b4, const float* __restrict__ b5) {
  const int proj = blockIdx.z;
  const u16* X = xh + (proj < 3 ? 0u : SZE);
  const u16* W = wt + (size_t)proj * 262144u;
  u16* out = qkv + (size_t)proj * SZE;
  const float* bias = proj == 0 ? b0 : proj == 1 ? b1 : proj == 2 ? b2
                    : proj == 3 ? b3 : proj == 4 ? b4 : b5;
  const int m0 = blockIdx.x * 128, n0 = blockIdx.y * 128;
  const int t = threadIdx.x, lane = t & 63, w = t >> 6;
  const int wr = w >> 1, wc = w & 1, ml = lane & 15, q = lane >> 4;
  __shared__ u16 sA[2][4096], sB[2][4096];  // row-major [128][32] per buffer
  fx4 acc[4][4] = {};
  // prologue: stage k-tile 0 into buffer 0 (dense: 4 lanes per 64B line)
  for (int r = 0; r < 2; ++r) {
    int ci = r * 256 + t;
    int row = ci >> 2, kc = ci & 3;
    gl2lds16(X + (size_t)(m0 + row) * 512 + kc * 8, sA[0] + ci * 8);
    gl2lds16(W + (size_t)(n0 + row) * 512 + kc * 8, sB[0] + ci * 8);
  }
  __syncthreads();
  for (int kt = 0; kt < 16; ++kt) {
    const int c = kt & 1;
    if (kt < 15) {
      const int k0 = (kt + 1) * 32;
      for (int r = 0; r < 2; ++r) {
        int ci = r * 256 + t;
        int row = ci >> 2, kc = ci & 3;
        gl2lds16(X + (size_t)(m0 + row) * 512 + (k0 + kc * 8), sA[c ^ 1] + ci * 8);
        gl2lds16(W + (size_t)(n0 + row) * 512 + (k0 + kc * 8), sB[c ^ 1] + ci * 8);
      }
    }
    f16x8 af[4], bf[4];
    for (int i = 0; i < 4; ++i) {
      af[i] = *(const f16x8*)(sA[c] + ((wr * 64 + i * 16 + ml) * 4 + q) * 8);
      bf[i] = *(const f16x8*)(sB[c] + ((wc * 64 + i * 16 + ml) * 4 + q) * 8);
    }
    for (int i = 0; i < 4; ++i)
      for (int j = 0; j < 4; ++j)
        acc[i][j] = __builtin_amdgcn_mfma_f32_16x16x32_f16(af[i], bf[j],
                                                           acc[i][j], 0, 0, 0);
    __syncthreads();
  }
  const int pm = proj % 3;  // 0=Q (row-major), 1=K blob, 2=V blob
  for (int j = 0; j < 4; ++j) {
    const int n = n0 + wc * 64 + j * 16 + ml;
    const float bv = bias[n];
    for (int i = 0; i < 4; ++i) {
      const int mb = m0 + wr * 64 + i * 16 + q * 4;
      if (pm == 0) {
        for (int r = 0; r < 4; ++r)
          out[(size_t)(mb + r) * 512 + n] = f2h_bits(acc[i][j][r] + bv);
      } else if (pm == 1) {
        for (int r = 0; r < 4; ++r) {
          const int m = mb + r, kq = m & 2047;
          size_t a = (size_t)(m >> 11) * 1048576u + (size_t)(kq >> 5) * 16384u
                   + (size_t)((n >> 3) * 32 + (kq & 31)) * 8u + (size_t)(n & 7);
          out[a] = f2h_bits(acc[i][j][r] + bv);
        }
      } else {
        const int l = mb & 2047;
        size_t a = (size_t)(mb >> 11) * 1048576u + (size_t)(l >> 5) * 16384u
                 + (size_t)(((l & 31) >> 3) * 512 + n) * 8u + (size_t)(l & 7);
        u16x4 pk;
        for (int r = 0; r < 4; ++r) pk[r] = f2h_bits(acc[i][j][r] + bv);
        *(u16x4*)(out + a) = pk;
      }
    }
  }
}

// ---------------- kernel 4: flash cross-attention v14 (proven, 216us) ------
// Tile-blob staging + setprio + DPP softmax reduces. Straight-line softmax;
// no control-flow-dependent live state around acc (v12 spill lesson).
__global__ __launch_bounds__(512, 2) void attn_kernel(const u16* __restrict__ qkv,
                                                      float* __restrict__ out) {
  const int t = threadIdx.x, lane = t & 63, w = t >> 6;  // w in 0..7
  const int ml = lane & 15, q = lane >> 4;
  // XCD swizzle: xcd = n&7 owns (b,tt) groups {2*xcd, 2*xcd+1}
  const int n = blockIdx.x;
  const int xcd = n & 7, slot = n >> 3;
  const int g = xcd * 2 + (slot >> 4);
  const int qt = slot & 15;
  const int b = g >> 1, tt = g & 1;

  const u16* Q  = qkv + (tt ? (size_t)3 * SZE : (size_t)0);
  const u16* K  = qkv + (tt ? (size_t)1 * SZE : (size_t)4 * SZE);
  const u16* Vt = qkv + (tt ? (size_t)5 * SZE : (size_t)2 * SZE);
  float* O = out + (tt ? (size_t)SZE : (size_t)0) +
             ((size_t)b * 2048 + qt * 128) * 512;
  const u16* Qb = Q + ((size_t)b * 2048 + qt * 128) * 512;
  const u16* Kb = K + (size_t)b * 1048576u;   // blob: [kt(64)][16384]
  const u16* Vb = Vt + (size_t)b * 1048576u;  // blob: [kt(64)][16384]

  __shared__ u16 sK[2][16384];   // 2 x 32KB, slot p: [dchunk(64)][key(32)]
  __shared__ u16 sV[2][16384];   // 2 x 32KB, slot p: [kc(4)][d(512)]
  __shared__ u16 sP[8 * 640];    // per-wave 16 rows x stride 40

  // Q A-frags for this wave's 16 rows (64 VGPR, resident all 64 iters)
  f16x8 qf[16];
  {
    const u16* qrow = Qb + (size_t)(w * 16 + ml) * 512 + q * 8;
#pragma unroll
    for (int ks = 0; ks < 16; ++ks) qf[ks] = *(const f16x8*)(qrow + ks * 32);
  }

  fx4 acc[32] = {};  // rows q*4+r (of wave's 16), col nj*16+ml  (128 VGPR)
  fx4 mrun = {-3.0e38f, -3.0e38f, -3.0e38f, -3.0e38f};
  fx4 lrun = {0.f, 0.f, 0.f, 0.f};
  u16* wp = sP + w * 640;

  // prestage tile 0 (linear: lane-consecutive 16B, fully coalesced)
#pragma unroll
  for (int r = 0; r < 4; ++r) {
    int p = r * 512 + t;
    gl2lds16(Kb + (size_t)p * 8, sK[0] + p * 8);
    gl2lds16(Vb + (size_t)p * 8, sV[0] + p * 8);
  }
  __syncthreads();

  for (int it = 0; it < 64; ++it) {
    const int c = it & 1;
    const u16* sKc = sK[c];
    const u16* sVc = sV[c];
    // ---- stage tile it+1 (linear blob reads); drained at end barrier ----
    if (it < 63) {
      const u16* Kn = Kb + (size_t)(it + 1) * 16384u;
      const u16* Vn = Vb + (size_t)(it + 1) * 16384u;
#pragma unroll
      for (int r = 0; r < 4; ++r) {
        int p = r * 512 + t;
        gl2lds16(Kn + (size_t)p * 8, sK[c ^ 1] + p * 8);
        gl2lds16(Vn + (size_t)p * 8, sV[c ^ 1] + p * 8);
      }
    }
    // ---- QK^T: this wave's 16 rows x 32 keys ----
    fx4 s0 = {0.f, 0.f, 0.f, 0.f}, s1 = {0.f, 0.f, 0.f, 0.f};
    __builtin_amdgcn_s_setprio(1);
#pragma unroll
    for (int ks = 0; ks < 16; ++ks) {
      f16x8 kf0 = *(const f16x8*)(sKc + ((ks * 4 + q) * 32 + ml) * 8);
      f16x8 kf1 = *(const f16x8*)(sKc + ((ks * 4 + q) * 32 + 16 + ml) * 8);
      s0 = __builtin_amdgcn_mfma_f32_16x16x32_f16(qf[ks], kf0, s0, 0, 0, 0);
      s1 = __builtin_amdgcn_mfma_f32_16x16x32_f16(qf[ks], kf1, s1, 0, 0, 0);
    }
    __builtin_amdgcn_s_setprio(0);
    // ---- online softmax, state in regs; DPP reduces (VALU pipe) ----
    fx4 mx, alpha, p0, p1, sm;
#pragma unroll
    for (int r = 0; r < 4; ++r) mx[r] = rowmax16(fmaxf(s0[r], s1[r]));
    bool need = false;
#pragma unroll
    for (int r = 0; r < 4; ++r) {
      float mn = fmaxf(mrun[r], mx[r]);
      alpha[r] = __expf(mrun[r] - mn);
      mrun[r] = mn;
      p0[r] = __expf(s0[r] - mn);
      p1[r] = __expf(s1[r] - mn);
      need |= (alpha[r] != 1.0f);
    }
#pragma unroll
    for (int r = 0; r < 4; ++r) sm[r] = rowsum16(p0[r] + p1[r]);
#pragma unroll
    for (int r = 0; r < 4; ++r) lrun[r] = alpha[r] * lrun[r] + sm[r];
    // ---- P -> wave-private slab (no barrier: same-wave lgkm ordering) ----
#pragma unroll
    for (int r = 0; r < 4; ++r) {
      wp[(q * 4 + r) * 40 + ml] = f2h_bits(p0[r]);
      wp[(q * 4 + r) * 40 + 16 + ml] = f2h_bits(p1[r]);
    }
    // ---- rescale acc (skip when no row saw a new max) ----
    if (__any(need)) {
#pragma unroll
      for (int nj = 0; nj < 32; ++nj) {
        acc[nj][0] *= alpha[0]; acc[nj][1] *= alpha[1];
        acc[nj][2] *= alpha[2]; acc[nj][3] *= alpha[3];
      }
    }
    f16x8 pf = *(const f16x8*)(wp + ml * 40 + q * 8);
    // ---- PV over all 512 d (one shared pf) ----
    __builtin_amdgcn_s_setprio(1);
#pragma unroll
    for (int nj = 0; nj < 32; ++nj) {
      f16x8 vf = *(const f16x8*)(sVc + (q * 512 + nj * 16 + ml) * 8);
      acc[nj] = __builtin_amdgcn_mfma_f32_16x16x32_f16(pf, vf, acc[nj], 0, 0, 0);
    }
    __builtin_amdgcn_s_setprio(0);
    __syncthreads();  // single barrier: drains next-iter staging + buffer flip
  }
  // ---- epilogue: O = acc / l (all wave-private) ----
  fx4 linv;
#pragma unroll
  for (int r = 0; r < 4; ++r) linv[r] = 1.0f / lrun[r];
  float* Ob = O + (size_t)(w * 16 + q * 4) * 512 + ml;
#pragma unroll
  for (int nj = 0; nj < 32; ++nj) {
#pragma unroll
    for (int r = 0; r < 4; ++r)
      Ob[(size_t)r * 512 + nj * 16] = acc[nj][r] * linv[r];
  }
}

extern "C" void kernel_launch(void* const* d_in, const int* in_sizes, int n_in,
                              void* d_out, int out_size, void* d_ws, size_t ws_size,
                              hipStream_t stream) {
  // ws layout (u16 elems): [xh: 2*SZE][wt: 6*512*512][qkv: 6*SZE]
  //   qkv order: 0=Qr 1=Kr(blob) 2=Vr^T(blob) 3=Qh 4=Kh(blob) 5=Vh^T(blob)
  u16* ws = (u16*)d_ws;
  u16* xh = ws;
  u16* wt = ws + 16777216u;            // 2*SZE
  u16* qkv = ws + 18350080u;           // 2*SZE + 6*262144

  convert_x<<<8192, 256, 0, stream>>>((const float*)d_in[0],
                                      (const float*)d_in[1], xh);
  wtrans<<<dim3(16, 16, 6), dim3(32, 8), 0, stream>>>(
      (const float*)d_in[2], (const float*)d_in[4], (const float*)d_in[6],
      (const float*)d_in[8], (const float*)d_in[10], (const float*)d_in[12], wt);
  proj_gemm<<<dim3(128, 4, 6), 256, 0, stream>>>(
      xh, wt, qkv,
      (const float*)d_in[3], (const float*)d_in[5], (const float*)d_in[7],
      (const float*)d_in[9], (const float*)d_in[11], (const float*)d_in[13]);
  attn_kernel<<<256, 512, 0, stream>>>(qkv, (float*)d_out);
}

// Round 17
// 394.264 us; speedup vs baseline: 1.2113x; 1.0749x over previous
//
#include <hip/hip_runtime.h>

typedef unsigned short u16;
typedef _Float16 f16;
typedef __attribute__((ext_vector_type(8))) f16 f16x8;
typedef __attribute__((ext_vector_type(4))) float fx4;
typedef __attribute__((ext_vector_type(8))) u16 u16x8;
typedef __attribute__((ext_vector_type(4))) u16 u16x4;

#define SZE 8388608u  // 16384*512 elements per [B*L, D] matrix

__device__ __forceinline__ u16 f2h_bits(float x) {
  union { f16 h; u16 u; } v; v.h = (f16)x; return v.u;
}

// async global->LDS, 16B per lane; dest is wave-uniform base + lane*16.
__device__ __forceinline__ void gl2lds16(const void* g, void* l) {
  __builtin_amdgcn_global_load_lds(
      (const __attribute__((address_space(1))) unsigned int*)g,
      (__attribute__((address_space(3))) unsigned int*)l, 16, 0, 0);
}

// ---- DPP 16-lane all-reduce (VALU-only; replaces ds_bpermute shfl chains).
// Reduce domain = 16 contiguous lanes (q*16..q*16+15) = one DPP row.
// quad_perm[1,0,3,2]=0xB1 (xor1), quad_perm[2,3,0,1]=0x4E (xor2); after
// those values are quad-uniform, so row_half_mirror(0x141) acts as xor4 and
// row_mirror(0x140) as xor8. Measured R13: attn 234->216us, MfmaUtil 24.7->28.
template <int C>
__device__ __forceinline__ float dppf(float x) {
  return __int_as_float(__builtin_amdgcn_update_dpp(
      __float_as_int(x), __float_as_int(x), C, 0xf, 0xf, false));
}
__device__ __forceinline__ float rowmax16(float x) {
  x = fmaxf(x, dppf<0xB1>(x));
  x = fmaxf(x, dppf<0x4E>(x));
  x = fmaxf(x, dppf<0x141>(x));
  x = fmaxf(x, dppf<0x140>(x));
  return x;
}
__device__ __forceinline__ float rowsum16(float x) {
  x += dppf<0xB1>(x);
  x += dppf<0x4E>(x);
  x += dppf<0x141>(x);
  x += dppf<0x140>(x);
  return x;
}

// ---------------- kernel 1: fp32 -> fp16 convert of both inputs ------------
__global__ __launch_bounds__(256) void convert_x(const float* __restrict__ x0,
                                                 const float* __restrict__ x1,
                                                 u16* __restrict__ xh) {
  size_t i = ((size_t)blockIdx.x * 256 + threadIdx.x) * 8;
  const float* src = (i < SZE) ? (x0 + i) : (x1 + (i - SZE));
  float4 a = *(const float4*)(src);
  float4 b = *(const float4*)(src + 4);
  u16x8 o;
  o[0] = f2h_bits(a.x); o[1] = f2h_bits(a.y);
  o[2] = f2h_bits(a.z); o[3] = f2h_bits(a.w);
  o[4] = f2h_bits(b.x); o[5] = f2h_bits(b.y);
  o[6] = f2h_bits(b.z); o[7] = f2h_bits(b.w);
  *(u16x8*)(xh + i) = o;
}

// ---------------- kernel 2: W [K][N] fp32 -> Wt [N][K] fp16 ----------------
__global__ __launch_bounds__(256) void wtrans(
    const float* __restrict__ w0, const float* __restrict__ w1,
    const float* __restrict__ w2, const float* __restrict__ w3,
    const float* __restrict__ w4, const float* __restrict__ w5,
    u16* __restrict__ wt) {
  __shared__ float tile[32][33];
  const int z = blockIdx.z;
  const float* W = z == 0 ? w0 : z == 1 ? w1 : z == 2 ? w2
                 : z == 3 ? w3 : z == 4 ? w4 : w5;
  u16* WT = wt + (size_t)z * 262144u;
  const int k0 = blockIdx.x * 32, n0 = blockIdx.y * 32;
  const int tx = threadIdx.x, ty = threadIdx.y;  // 32 x 8
  for (int j = 0; j < 32; j += 8)
    tile[ty + j][tx] = W[(size_t)(k0 + ty + j) * 512 + n0 + tx];
  __syncthreads();
  for (int j = 0; j < 32; j += 8)
    WT[(size_t)(n0 + ty + j) * 512 + k0 + tx] = f2h_bits(tile[tx][ty + j]);
}

// ---------------- kernel 3: six projections, C = X*W + b -------------------
// R16 dense staging (confirmed -37us) + EPILOGUE STORE FIX, retested in the
// new regime (R8's null was measured while loads dominated -- rule #23).
// Q and K paths: stage the C-tile in the k-loop's own 32KB LDS (dead after
// the final barrier; aliased, so LDS stays 32KB and 3 blocks/CU is kept,
// unlike R8's +33KB version), then copy out with dense u16x8 stores (every
// 64B line written whole) -- replaces 64 scalar 2B global stores/thread
// with 8 vector stores. V path unchanged (already 8B-vectorized).
// Output blob layouts (consumed linearly by attn staging):
//  K blob: per b, per 32-key tile kt: slot p = dchunk*32+key holds
//          K[key][dchunk*8 .. +8).
//  V blob: per b, per tile kt: slot p = kc*512 + d holds
//          V[token kt*32+kc*8 .. +8)[d].
__global__ __launch_bounds__(256, 3) void proj_gemm(
    const u16* __restrict__ xh, const u16* __restrict__ wt,
    u16* __restrict__ qkv,
    const float* __restrict__ b0, const float* __restrict__ b1,
    const float* __restrict__ b2, const float* __restrict__ b3,
    const float* __restrict__ b4, const float* __restrict__ b5) {
  const int proj = blockIdx.z;
  const u16* X = xh + (proj < 3 ? 0u : SZE);
  const u16* W = wt + (size_t)proj * 262144u;
  u16* out = qkv + (size_t)proj * SZE;
  const float* bias = proj == 0 ? b0 : proj == 1 ? b1 : proj == 2 ? b2
                    : proj == 3 ? b3 : proj == 4 ? b4 : b5;
  const int m0 = blockIdx.x * 128, n0 = blockIdx.y * 128;
  const int t = threadIdx.x, lane = t & 63, w = t >> 6;
  const int wr = w >> 1, wc = w & 1, ml = lane & 15, q = lane >> 4;
  // 32KB: k-loop double buffers; reused as C-stage after the final barrier.
  __shared__ u16 smem[16384];
  u16* sAb[2] = {smem, smem + 4096};
  u16* sBb[2] = {smem + 8192, smem + 12288};
  fx4 acc[4][4] = {};
  // prologue: stage k-tile 0 into buffer 0 (dense: 4 lanes per 64B line)
  for (int r = 0; r < 2; ++r) {
    int ci = r * 256 + t;
    int row = ci >> 2, kc = ci & 3;
    gl2lds16(X + (size_t)(m0 + row) * 512 + kc * 8, sAb[0] + ci * 8);
    gl2lds16(W + (size_t)(n0 + row) * 512 + kc * 8, sBb[0] + ci * 8);
  }
  __syncthreads();
  for (int kt = 0; kt < 16; ++kt) {
    const int c = kt & 1;
    if (kt < 15) {
      const int k0 = (kt + 1) * 32;
      for (int r = 0; r < 2; ++r) {
        int ci = r * 256 + t;
        int row = ci >> 2, kc = ci & 3;
        gl2lds16(X + (size_t)(m0 + row) * 512 + (k0 + kc * 8), sAb[c ^ 1] + ci * 8);
        gl2lds16(W + (size_t)(n0 + row) * 512 + (k0 + kc * 8), sBb[c ^ 1] + ci * 8);
      }
    }
    f16x8 af[4], bf[4];
    for (int i = 0; i < 4; ++i) {
      af[i] = *(const f16x8*)(sAb[c] + ((wr * 64 + i * 16 + ml) * 4 + q) * 8);
      bf[i] = *(const f16x8*)(sBb[c] + ((wc * 64 + i * 16 + ml) * 4 + q) * 8);
    }
    for (int i = 0; i < 4; ++i)
      for (int j = 0; j < 4; ++j)
        acc[i][j] = __builtin_amdgcn_mfma_f32_16x16x32_f16(af[i], bf[j],
                                                           acc[i][j], 0, 0, 0);
    __syncthreads();  // final iteration: also fences k-loop reads vs C-stage
  }
  const int pm = proj % 3;  // 0=Q (row-major), 1=K blob, 2=V blob
  if (pm == 2) {
    // V blob: direct u16x4 stores (unchanged; already vectorized)
    for (int j = 0; j < 4; ++j) {
      const int n = n0 + wc * 64 + j * 16 + ml;
      const float bv = bias[n];
      for (int i = 0; i < 4; ++i) {
        const int mb = m0 + wr * 64 + i * 16 + q * 4;
        const int l = mb & 2047;
        size_t a = (size_t)(mb >> 11) * 1048576u + (size_t)(l >> 5) * 16384u
                 + (size_t)(((l & 31) >> 3) * 512 + n) * 8u + (size_t)(l & 7);
        u16x4 pk;
        for (int r = 0; r < 4; ++r) pk[r] = f2h_bits(acc[i][j][r] + bv);
        *(u16x4*)(out + a) = pk;
      }
    }
  } else {
    if (pm == 0) {
      // stage row-major [128][128]
      for (int j = 0; j < 4; ++j) {
        const float bv = bias[n0 + wc * 64 + j * 16 + ml];
        for (int i = 0; i < 4; ++i) {
          const int lm = wr * 64 + i * 16 + q * 4;
          const int ln = wc * 64 + j * 16 + ml;
          for (int r = 0; r < 4; ++r)
            smem[(lm + r) * 128 + ln] = f2h_bits(acc[i][j][r] + bv);
        }
      }
    } else {
      // stage in exact K-blob order [kt2(4)][dcl(16)][key(32)][d8(8)]
      for (int j = 0; j < 4; ++j) {
        const float bv = bias[n0 + wc * 64 + j * 16 + ml];
        for (int i = 0; i < 4; ++i) {
          const int kt2 = wr * 2 + (i >> 1);
          const int key5 = (i & 1) * 16 + q * 4;
          const int dcl = wc * 8 + j * 2 + (ml >> 3);
          const int d8 = ml & 7;
          u16* cb = smem + kt2 * 4096 + dcl * 256 + d8;
          for (int r = 0; r < 4; ++r)
            cb[(key5 + r) * 8] = f2h_bits(acc[i][j][r] + bv);
        }
      }
    }
    __syncthreads();
    // dense copy-out: 2048 x 16B chunks, consecutive lanes -> whole lines
    if (pm == 0) {
      for (int s = 0; s < 8; ++s) {
        int ci = s * 256 + t;
        int row = ci >> 4, c8 = ci & 15;
        *(u16x8*)(out + (size_t)(m0 + row) * 512 + n0 + c8 * 8) =
            *(const u16x8*)(smem + ci * 8);
      }
    } else {
      const size_t bbase = (size_t)(m0 >> 11) * 1048576u +
                           (size_t)((m0 & 2047) >> 5) * 16384u +
                           (size_t)(n0 >> 3) * 256u;
      for (int s = 0; s < 8; ++s) {
        int ci = s * 256 + t;
        int kt2 = ci >> 9, inner = ci & 511;
        *(u16x8*)(out + bbase + (size_t)kt2 * 16384u + inner * 8) =
            *(const u16x8*)(smem + ci * 8);
      }
    }
  }
}

// ---------------- kernel 4: flash cross-attention v14 (proven, 216us) ------
// Tile-blob staging + setprio + DPP softmax reduces. Straight-line softmax;
// no control-flow-dependent live state around acc (v12 spill lesson).
__global__ __launch_bounds__(512, 2) void attn_kernel(const u16* __restrict__ qkv,
                                                      float* __restrict__ out) {
  const int t = threadIdx.x, lane = t & 63, w = t >> 6;  // w in 0..7
  const int ml = lane & 15, q = lane >> 4;
  // XCD swizzle: xcd = n&7 owns (b,tt) groups {2*xcd, 2*xcd+1}
  const int n = blockIdx.x;
  const int xcd = n & 7, slot = n >> 3;
  const int g = xcd * 2 + (slot >> 4);
  const int qt = slot & 15;
  const int b = g >> 1, tt = g & 1;

  const u16* Q  = qkv + (tt ? (size_t)3 * SZE : (size_t)0);
  const u16* K  = qkv + (tt ? (size_t)1 * SZE : (size_t)4 * SZE);
  const u16* Vt = qkv + (tt ? (size_t)5 * SZE : (size_t)2 * SZE);
  float* O = out + (tt ? (size_t)SZE : (size_t)0) +
             ((size_t)b * 2048 + qt * 128) * 512;
  const u16* Qb = Q + ((size_t)b * 2048 + qt * 128) * 512;
  const u16* Kb = K + (size_t)b * 1048576u;   // blob: [kt(64)][16384]
  const u16* Vb = Vt + (size_t)b * 1048576u;  // blob: [kt(64)][16384]

  __shared__ u16 sK[2][16384];   // 2 x 32KB, slot p: [dchunk(64)][key(32)]
  __shared__ u16 sV[2][16384];   // 2 x 32KB, slot p: [kc(4)][d(512)]
  __shared__ u16 sP[8 * 640];    // per-wave 16 rows x stride 40

  // Q A-frags for this wave's 16 rows (64 VGPR, resident all 64 iters)
  f16x8 qf[16];
  {
    const u16* qrow = Qb + (size_t)(w * 16 + ml) * 512 + q * 8;
#pragma unroll
    for (int ks = 0; ks < 16; ++ks) qf[ks] = *(const f16x8*)(qrow + ks * 32);
  }

  fx4 acc[32] = {};  // rows q*4+r (of wave's 16), col nj*16+ml  (128 VGPR)
  fx4 mrun = {-3.0e38f, -3.0e38f, -3.0e38f, -3.0e38f};
  fx4 lrun = {0.f, 0.f, 0.f, 0.f};
  u16* wp = sP + w * 640;

  // prestage tile 0 (linear: lane-consecutive 16B, fully coalesced)
#pragma unroll
  for (int r = 0; r < 4; ++r) {
    int p = r * 512 + t;
    gl2lds16(Kb + (size_t)p * 8, sK[0] + p * 8);
    gl2lds16(Vb + (size_t)p * 8, sV[0] + p * 8);
  }
  __syncthreads();

  for (int it = 0; it < 64; ++it) {
    const int c = it & 1;
    const u16* sKc = sK[c];
    const u16* sVc = sV[c];
    // ---- stage tile it+1 (linear blob reads); drained at end barrier ----
    if (it < 63) {
      const u16* Kn = Kb + (size_t)(it + 1) * 16384u;
      const u16* Vn = Vb + (size_t)(it + 1) * 16384u;
#pragma unroll
      for (int r = 0; r < 4; ++r) {
        int p = r * 512 + t;
        gl2lds16(Kn + (size_t)p * 8, sK[c ^ 1] + p * 8);
        gl2lds16(Vn + (size_t)p * 8, sV[c ^ 1] + p * 8);
      }
    }
    // ---- QK^T: this wave's 16 rows x 32 keys ----
    fx4 s0 = {0.f, 0.f, 0.f, 0.f}, s1 = {0.f, 0.f, 0.f, 0.f};
    __builtin_amdgcn_s_setprio(1);
#pragma unroll
    for (int ks = 0; ks < 16; ++ks) {
      f16x8 kf0 = *(const f16x8*)(sKc + ((ks * 4 + q) * 32 + ml) * 8);
      f16x8 kf1 = *(const f16x8*)(sKc + ((ks * 4 + q) * 32 + 16 + ml) * 8);
      s0 = __builtin_amdgcn_mfma_f32_16x16x32_f16(qf[ks], kf0, s0, 0, 0, 0);
      s1 = __builtin_amdgcn_mfma_f32_16x16x32_f16(qf[ks], kf1, s1, 0, 0, 0);
    }
    __builtin_amdgcn_s_setprio(0);
    // ---- online softmax, state in regs; DPP reduces (VALU pipe) ----
    fx4 mx, alpha, p0, p1, sm;
#pragma unroll
    for (int r = 0; r < 4; ++r) mx[r] = rowmax16(fmaxf(s0[r], s1[r]));
    bool need = false;
#pragma unroll
    for (int r = 0; r < 4; ++r) {
      float mn = fmaxf(mrun[r], mx[r]);
      alpha[r] = __expf(mrun[r] - mn);
      mrun[r] = mn;
      p0[r] = __expf(s0[r] - mn);
      p1[r] = __expf(s1[r] - mn);
      need |= (alpha[r] != 1.0f);
    }
#pragma unroll
    for (int r = 0; r < 4; ++r) sm[r] = rowsum16(p0[r] + p1[r]);
#pragma unroll
    for (int r = 0; r < 4; ++r) lrun[r] = alpha[r] * lrun[r] + sm[r];
    // ---- P -> wave-private slab (no barrier: same-wave lgkm ordering) ----
#pragma unroll
    for (int r = 0; r < 4; ++r) {
      wp[(q * 4 + r) * 40 + ml] = f2h_bits(p0[r]);
      wp[(q * 4 + r) * 40 + 16 + ml] = f2h_bits(p1[r]);
    }
    // ---- rescale acc (skip when no row saw a new max) ----
    if (__any(need)) {
#pragma unroll
      for (int nj = 0; nj < 32; ++nj) {
        acc[nj][0] *= alpha[0]; acc[nj][1] *= alpha[1];
        acc[nj][2] *= alpha[2]; acc[nj][3] *= alpha[3];
      }
    }
    f16x8 pf = *(const f16x8*)(wp + ml * 40 + q * 8);
    // ---- PV over all 512 d (one shared pf) ----
    __builtin_amdgcn_s_setprio(1);
#pragma unroll
    for (int nj = 0; nj < 32; ++nj) {
      f16x8 vf = *(const f16x8*)(sVc + (q * 512 + nj * 16 + ml) * 8);
      acc[nj] = __builtin_amdgcn_mfma_f32_16x16x32_f16(pf, vf, acc[nj], 0, 0, 0);
    }
    __builtin_amdgcn_s_setprio(0);
    __syncthreads();  // single barrier: drains next-iter staging + buffer flip
  }
  // ---- epilogue: O = acc / l (all wave-private) ----
  fx4 linv;
#pragma unroll
  for (int r = 0; r < 4; ++r) linv[r] = 1.0f / lrun[r];
  float* Ob = O + (size_t)(w * 16 + q * 4) * 512 + ml;
#pragma unroll
  for (int nj = 0; nj < 32; ++nj) {
#pragma unroll
    for (int r = 0; r < 4; ++r)
      Ob[(size_t)r * 512 + nj * 16] = acc[nj][r] * linv[r];
  }
}

extern "C" void kernel_launch(void* const* d_in, const int* in_sizes, int n_in,
                              void* d_out, int out_size, void* d_ws, size_t ws_size,
                              hipStream_t stream) {
  // ws layout (u16 elems): [xh: 2*SZE][wt: 6*512*512][qkv: 6*SZE]
  //   qkv order: 0=Qr 1=Kr(blob) 2=Vr^T(blob) 3=Qh 4=Kh(blob) 5=Vh^T(blob)
  u16* ws = (u16*)d_ws;
  u16* xh = ws;
  u16* wt = ws + 16777216u;            // 2*SZE
  u16* qkv = ws + 18350080u;           // 2*SZE + 6*262144

  convert_x<<<8192, 256, 0, stream>>>((const float*)d_in[0],
                                      (const float*)d_in[1], xh);
  wtrans<<<dim3(16, 16, 6), dim3(32, 8), 0, stream>>>(
      (const float*)d_in[2], (const float*)d_in[4], (const float*)d_in[6],
      (const float*)d_in[8], (const float*)d_in[10], (const float*)d_in[12], wt);
  proj_gemm<<<dim3(128, 4, 6), 256, 0, stream>>>(
      xh, wt, qkv,
      (const float*)d_in[3], (const float*)d_in[5], (const float*)d_in[7],
      (const float*)d_in[9], (const float*)d_in[11], (const float*)d_in[13]);
  attn_kernel<<<256, 512, 0, stream>>>(qkv, (float*)d_out);
}